// Round 1
// baseline (365.320 us; speedup 1.0000x reference)
//
#include <hip/hip_runtime.h>
#include <stdint.h>

// Problem constants (fixed by the reference).
#define NN   200000   // nodes
#define NTOT 200001   // nodes + sentinel

typedef short bf16x8 __attribute__((ext_vector_type(8)));   // 8 bf16 = 4 VGPRs
typedef float f32x16 __attribute__((ext_vector_type(16)));  // 32x32 MFMA acc

union FragU { bf16x8 v; unsigned q[4]; };

// float -> bf16 round-to-nearest-even (finite inputs)
__device__ __forceinline__ unsigned bfrne(float x) {
  unsigned u = __float_as_uint(x);
  return (u + 0x7fffu + ((u >> 16) & 1u)) >> 16;
}
__device__ __forceinline__ unsigned pk2(float a, float b) {
  return bfrne(a) | (bfrne(b) << 16);
}
__device__ __forceinline__ unsigned shx32(unsigned x) {
  return (unsigned)__shfl_xor((int)x, 32, 64);
}

// ---------------------------------------------------------------------------
// prep: c0 = f0^T W0[:256] + b0 (fp32); score for zero-neighbor rows (idx 0 and
// sentinel); W0n^T and W1^T converted to bf16, stored [out][k] with 16B atoms
// XOR-swizzled (atom a stored at a ^ (row&7)) for conflict-free ds_read_b128.
// ---------------------------------------------------------------------------
__global__ void gnn_prep(const float* __restrict__ feat, const float* __restrict__ W0,
                         const float* __restrict__ b0, const float* __restrict__ W1,
                         const float* __restrict__ b1, const float* __restrict__ wsc,
                         float* __restrict__ c0g, char* __restrict__ w0t,
                         char* __restrict__ w1t, float* __restrict__ scores,
                         float* __restrict__ S, int* __restrict__ cnt)
{
  const int tid = threadIdx.x;
  if (blockIdx.x == 0) {
    __shared__ float h0z[256];
    __shared__ float h1z[128];
    float a = b0[tid];
    for (int f = 0; f < 256; ++f) a = fmaf(feat[f], W0[f * 256 + tid], a);
    c0g[tid] = a;
    h0z[tid] = fmaxf(a, 0.f);
    __syncthreads();
    if (tid < 128) {
      float t = b1[tid];
      for (int k = 0; k < 256; ++k) t = fmaf(h0z[k], W1[k * 128 + tid], t);
      h1z[tid] = fmaxf(t, 0.f) * wsc[tid];
    }
    __syncthreads();
    if (tid == 0) {
      float sz = 0.f;
      for (int p = 0; p < 128; ++p) sz += h1z[p];
      scores[0]  = sz;   // node 0 uses zero neighbor in the reference
      scores[NN] = sz;   // sentinel row
      *S = 0.f;
      *cnt = 0;
    }
  } else {
    int gid = (blockIdx.x - 1) * 256 + tid;
    if (gid < 8192) {              // W0 neighbor-half transpose: [256 out][256 k]
      int m = gid >> 5, a = gid & 31, k0 = a * 8;
      unsigned q0 = pk2(W0[(256 + k0 + 0) * 256 + m], W0[(256 + k0 + 1) * 256 + m]);
      unsigned q1 = pk2(W0[(256 + k0 + 2) * 256 + m], W0[(256 + k0 + 3) * 256 + m]);
      unsigned q2 = pk2(W0[(256 + k0 + 4) * 256 + m], W0[(256 + k0 + 5) * 256 + m]);
      unsigned q3 = pk2(W0[(256 + k0 + 6) * 256 + m], W0[(256 + k0 + 7) * 256 + m]);
      *(uint4*)(w0t + m * 512 + ((a ^ (m & 7)) << 4)) = make_uint4(q0, q1, q2, q3);
    } else if (gid < 12288) {      // W1 transpose: [128 out][256 k]
      int g2 = gid - 8192;
      int p = g2 >> 5, a = g2 & 31, k0 = a * 8;
      unsigned q0 = pk2(W1[(k0 + 0) * 128 + p], W1[(k0 + 1) * 128 + p]);
      unsigned q1 = pk2(W1[(k0 + 2) * 128 + p], W1[(k0 + 3) * 128 + p]);
      unsigned q2 = pk2(W1[(k0 + 4) * 128 + p], W1[(k0 + 5) * 128 + p]);
      unsigned q3 = pk2(W1[(k0 + 6) * 128 + p], W1[(k0 + 7) * 128 + p]);
      *(uint4*)(w1t + p * 512 + ((a ^ (p & 7)) << 4)) = make_uint4(q0, q1, q2, q3);
    }
  }
}

// ---------------------------------------------------------------------------
// compact: idx[] = columns i in [1, NN) with adj[i] != 0 (order irrelevant).
// ---------------------------------------------------------------------------
__global__ void gnn_compact(const int* __restrict__ adj, int* __restrict__ idx,
                            int* __restrict__ cnt)
{
  int i = blockIdx.x * blockDim.x + threadIdx.x;
  bool f = (i > 0) && (i < NN) && (adj[i] != 0);
  unsigned long long m = __ballot(f);
  int lane = threadIdx.x & 63;
  int tot = __popcll(m);
  int base = 0;
  if (lane == 0 && tot) base = atomicAdd(cnt, tot);
  base = __shfl(base, 0, 64);
  if (f) idx[base + __popcll(m & ((1ull << lane) - 1ull))] = i;
}

// ---------------------------------------------------------------------------
// main fused MLP: block = 256 thr (4 waves), 128 compacted rows/block (32/wave).
// MFMA operands swapped: A = weight^T tiles (LDS, global_load_lds dwordx4,
// swizzled), B = per-node data (registers). Layer-1 C-layout (col = node)
// converts to layer-2 B-fragments with shfl_xor(32) only.
// ---------------------------------------------------------------------------
__global__ __launch_bounds__(256, 2) void
gnn_main(const float* __restrict__ feat, const char* __restrict__ w0t,
         const char* __restrict__ w1t, const float* __restrict__ c0g,
         const float* __restrict__ b1, const float* __restrict__ wsc,
         const int* __restrict__ idx, const int* __restrict__ cnt,
         float* __restrict__ scores)
{
  __shared__ __align__(16) char sW[2][32768];  // weight chunk double buffer
  __shared__ float c0s[256];
  __shared__ float b1s[128];
  __shared__ float wss[128];

  const int M = *cnt;
  if ((int)blockIdx.x * 128 >= M) return;

  const int tid  = threadIdx.x;
  const int wave = tid >> 6, lane = tid & 63;
  const int h = lane >> 5, nl = lane & 31;

  const int slot = blockIdx.x * 128 + wave * 32 + nl;
  const int node = idx[min(slot, M - 1)];

  auto stage = [&](int buf, const char* gsrc) {
    const char* gp = gsrc + (wave << 13) + (lane << 4);
    char* lp = &sW[buf][wave << 13];
#pragma unroll
    for (int i = 0; i < 8; ++i)
      __builtin_amdgcn_global_load_lds(
          (const __attribute__((address_space(1))) unsigned*)(gp + (i << 10)),
          (__attribute__((address_space(3))) unsigned*)(lp + (i << 10)),
          16, 0, 0);
  };

  stage(0, w0t);  // chunk 0 (W0^T rows 0..63) async while we load features

  // Feature B-fragments: B[k][n]: n = lane&31 (node), k = 16*kk + 8*h + j.
  FragU fB[16];
  const float4* frow = (const float4*)(feat + (size_t)node * 256);
#pragma unroll
  for (int kk = 0; kk < 16; ++kk) {
    float4 x = frow[4 * kk + 2 * h];
    float4 y = frow[4 * kk + 2 * h + 1];
    fB[kk].q[0] = pk2(x.x, x.y);
    fB[kk].q[1] = pk2(x.z, x.w);
    fB[kk].q[2] = pk2(y.x, y.y);
    fB[kk].q[3] = pk2(y.z, y.w);
  }

  c0s[tid] = c0g[tid];
  if (tid < 128) { b1s[tid] = b1[tid]; wss[tid] = wsc[tid]; }
  __syncthreads();

  // ---- layer 1: h0 = relu(c0 + W0n^T f) ; packed bf16 kept in registers ----
  unsigned h0p[8][8];
#pragma unroll
  for (int c = 0; c < 4; ++c) {
    stage((c + 1) & 1, (c < 3) ? (w0t + (c + 1) * 32768) : w1t);
    const char* Bp = sW[c & 1];
    f32x16 acc0, acc1;
#pragma unroll
    for (int i = 0; i < 16; ++i) { acc0[i] = 0.f; acc1[i] = 0.f; }
#pragma unroll
    for (int kk = 0; kk < 16; ++kk) {
      // A[m'][k]: m' = lane&31 (row in chunk), atom = 2*kk + h, XOR-swizzled
      bf16x8 a0 = *(const bf16x8*)(Bp + nl * 512        + (((2 * kk + h) ^ (nl & 7)) << 4));
      bf16x8 a1 = *(const bf16x8*)(Bp + (32 + nl) * 512 + (((2 * kk + h) ^ (nl & 7)) << 4));
      acc0 = __builtin_amdgcn_mfma_f32_32x32x16_bf16(a0, fB[kk].v, acc0, 0, 0, 0);
      acc1 = __builtin_amdgcn_mfma_f32_32x32x16_bf16(a1, fB[kk].v, acc1, 0, 0, 0);
    }
#pragma unroll
    for (int t = 0; t < 2; ++t) {
      const f32x16& ac = t ? acc1 : acc0;
      const int tile = c * 2 + t, nb = tile * 32;
#pragma unroll
      for (int g = 0; g < 4; ++g) {
        // C/D row = (reg&3) + 8*(reg>>2) + 4*h ; col = node
        float4 cv = *(const float4*)&c0s[nb + 8 * g + 4 * h];
        float v0 = fmaxf(ac[4 * g + 0] + cv.x, 0.f);
        float v1 = fmaxf(ac[4 * g + 1] + cv.y, 0.f);
        float v2 = fmaxf(ac[4 * g + 2] + cv.z, 0.f);
        float v3 = fmaxf(ac[4 * g + 3] + cv.w, 0.f);
        h0p[tile][2 * g + 0] = pk2(v0, v1);
        h0p[tile][2 * g + 1] = pk2(v2, v3);
      }
    }
    __syncthreads();
  }

  // ---- convert h0 C-layout -> layer-2 B fragments (half-wave swap only) ----
  const bool hh = (h != 0);
#pragma unroll
  for (int tt = 0; tt < 8; ++tt) {
    unsigned o[8], s[8];
#pragma unroll
    for (int r = 0; r < 8; ++r) { o[r] = h0p[tt][r]; s[r] = shx32(o[r]); }
    h0p[tt][0] = hh ? s[2] : o[0];
    h0p[tt][1] = hh ? s[3] : o[1];
    h0p[tt][2] = hh ? o[2] : s[0];
    h0p[tt][3] = hh ? o[3] : s[1];
    h0p[tt][4] = hh ? s[6] : o[4];
    h0p[tt][5] = hh ? s[7] : o[5];
    h0p[tt][6] = hh ? o[6] : s[4];
    h0p[tt][7] = hh ? o[7] : s[5];
  }

  // ---- layer 2: h1 = relu(b1 + W1^T h0) ; score = h1 . w ----
  f32x16 acc2[4];
#pragma unroll
  for (int t = 0; t < 4; ++t)
#pragma unroll
    for (int i = 0; i < 16; ++i) acc2[t][i] = 0.f;

#pragma unroll
  for (int c2 = 0; c2 < 2; ++c2) {
    if (c2 == 0) stage(1, w1t + 32768);  // chunk 5 = W1^T rows 64..127
    const char* Bp = sW[c2];             // chunk 4 landed in buf 0, 5 in buf 1
#pragma unroll
    for (int kk = 0; kk < 16; ++kk) {
      bf16x8 a0 = *(const bf16x8*)(Bp + nl * 512        + (((2 * kk + h) ^ (nl & 7)) << 4));
      bf16x8 a1 = *(const bf16x8*)(Bp + (32 + nl) * 512 + (((2 * kk + h) ^ (nl & 7)) << 4));
      FragU bb;
      const int tt = kk >> 1, p = kk & 1;
      bb.q[0] = h0p[tt][4 * p + 0];
      bb.q[1] = h0p[tt][4 * p + 1];
      bb.q[2] = h0p[tt][4 * p + 2];
      bb.q[3] = h0p[tt][4 * p + 3];
      acc2[c2 * 2 + 0] = __builtin_amdgcn_mfma_f32_32x32x16_bf16(a0, bb.v, acc2[c2 * 2 + 0], 0, 0, 0);
      acc2[c2 * 2 + 1] = __builtin_amdgcn_mfma_f32_32x32x16_bf16(a1, bb.v, acc2[c2 * 2 + 1], 0, 0, 0);
    }
    if (c2 == 0) __syncthreads();
  }

  float sc = 0.f;
#pragma unroll
  for (int pt = 0; pt < 4; ++pt) {
#pragma unroll
    for (int g = 0; g < 4; ++g) {
      float4 bv = *(const float4*)&b1s[pt * 32 + 8 * g + 4 * h];
      float4 wv = *(const float4*)&wss[pt * 32 + 8 * g + 4 * h];
      sc += fmaxf(acc2[pt][4 * g + 0] + bv.x, 0.f) * wv.x;
      sc += fmaxf(acc2[pt][4 * g + 1] + bv.y, 0.f) * wv.y;
      sc += fmaxf(acc2[pt][4 * g + 2] + bv.z, 0.f) * wv.z;
      sc += fmaxf(acc2[pt][4 * g + 3] + bv.w, 0.f) * wv.w;
    }
  }
  sc += __shfl_xor(sc, 32, 64);  // combine the two p-halves (same node)
  if (h == 0 && slot < M) scores[node] = sc;
}

// ---------------------------------------------------------------------------
// masked sum of exp(scores) (scores are O(0.1): no max-subtraction needed)
// ---------------------------------------------------------------------------
__global__ void gnn_reduce(const int* __restrict__ adj, const float* __restrict__ scores,
                           float* __restrict__ S)
{
  float loc = 0.f;
  for (int i = blockIdx.x * blockDim.x + threadIdx.x; i <= NN;
       i += gridDim.x * blockDim.x) {
    bool m = (i == NN) || (adj[i] != 0);
    if (m) loc += expf(scores[i]);
  }
#pragma unroll
  for (int off = 32; off; off >>= 1) loc += __shfl_xor(loc, off, 64);
  __shared__ float part[4];
  if ((threadIdx.x & 63) == 0) part[threadIdx.x >> 6] = loc;
  __syncthreads();
  if (threadIdx.x == 0) atomicAdd(S, part[0] + part[1] + part[2] + part[3]);
}

__global__ void gnn_final(const int* __restrict__ adj, const float* __restrict__ scores,
                          const float* __restrict__ S, float* __restrict__ out)
{
  int i = blockIdx.x * blockDim.x + threadIdx.x;
  if (i > NN) return;
  bool m = (i == NN) || (adj[i] != 0);
  float Sv = *S;
  out[i] = m ? expf(scores[i]) / Sv : 0.f;
}

// ---------------------------------------------------------------------------
extern "C" void kernel_launch(void* const* d_in, const int* in_sizes, int n_in,
                              void* d_out, int out_size, void* d_ws, size_t ws_size,
                              hipStream_t stream)
{
  (void)in_sizes; (void)n_in; (void)out_size; (void)ws_size;
  const int*   adj  = (const int*)d_in[0];
  const float* feat = (const float*)d_in[1];
  const float* W0   = (const float*)d_in[2];
  const float* b0   = (const float*)d_in[3];
  const float* W1   = (const float*)d_in[4];
  const float* b1   = (const float*)d_in[5];
  const float* wsc  = (const float*)d_in[6];
  float* out = (float*)d_out;

  // workspace layout (≈1.8 MB)
  char* ws = (char*)d_ws;
  float* scores = (float*)ws;               // 200001 f32 (pad to 800256 B)
  char*  w0t    = ws + 800256;              // 131072 B  W0n^T bf16, swizzled
  char*  w1t    = ws + 931328;              // 65536 B   W1^T  bf16, swizzled
  float* c0g    = (float*)(ws + 996864);    // 256 f32
  float* S      = (float*)(ws + 997888);    // 1 f32
  int*   cnt    = (int*)(ws + 997904);      // 1 i32
  int*   idxb   = (int*)(ws + 997952);      // 200000 i32

  gnn_prep   <<<49,   256, 0, stream>>>(feat, W0, b0, W1, b1, wsc, c0g, w0t, w1t, scores, S, cnt);
  gnn_compact<<<782,  256, 0, stream>>>(adj, idxb, cnt);
  gnn_main   <<<1563, 256, 0, stream>>>(feat, w0t, w1t, c0g, b1, wsc, idxb, cnt, scores);
  gnn_reduce <<<512,  256, 0, stream>>>(adj, scores, S);
  gnn_final  <<<782,  256, 0, stream>>>(adj, scores, S, out);
}

// Round 2
// 321.670 us; speedup vs baseline: 1.1357x; 1.1357x over previous
//
#include <hip/hip_runtime.h>
#include <stdint.h>

// Problem constants (fixed by the reference).
#define NN   200000   // nodes
#define NTOT 200001   // nodes + sentinel

typedef short bf16x8 __attribute__((ext_vector_type(8)));   // 8 bf16 = 4 VGPRs
typedef float f32x16 __attribute__((ext_vector_type(16)));  // 32x32 MFMA acc

union FragU { bf16x8 v; unsigned q[4]; };

// float -> bf16 round-to-nearest-even (finite inputs)
__device__ __forceinline__ unsigned bfrne(float x) {
  unsigned u = __float_as_uint(x);
  return (u + 0x7fffu + ((u >> 16) & 1u)) >> 16;
}
__device__ __forceinline__ unsigned pk2(float a, float b) {
  return bfrne(a) | (bfrne(b) << 16);
}

// ---------------------------------------------------------------------------
// prep: c0 = f0^T W0[:256] + b0 (fp32); score for zero-neighbor rows (node 0
// and sentinel) and S seeded with their exp() contributions; W0n^T and W1^T
// converted to bf16, 16B atoms XOR-swizzled (atom a at a ^ (row&7)).
// w1t additionally bakes in the k-permutation that matches the layer-1 MFMA
// C-layout, so layer 2 consumes h0 registers with NO cross-lane shuffle:
// atom a (tt=a>>2, p'=(a>>1)&1, h=a&1), pos j holds k = 32tt+16p'+4h+8(j>>2)+(j&3).
// ---------------------------------------------------------------------------
__global__ void gnn_prep(const int* __restrict__ adj, const float* __restrict__ feat,
                         const float* __restrict__ W0, const float* __restrict__ b0,
                         const float* __restrict__ W1, const float* __restrict__ b1,
                         const float* __restrict__ wsc, float* __restrict__ c0g,
                         char* __restrict__ w0t, char* __restrict__ w1t,
                         float* __restrict__ scores, float* __restrict__ S,
                         int* __restrict__ cnt)
{
  const int tid = threadIdx.x;
  if (blockIdx.x == 0) {
    __shared__ float h0z[256];
    __shared__ float h1z[128];
    float a = b0[tid];
    for (int f = 0; f < 256; ++f) a = fmaf(feat[f], W0[f * 256 + tid], a);
    c0g[tid] = a;
    h0z[tid] = fmaxf(a, 0.f);
    __syncthreads();
    if (tid < 128) {
      float t = b1[tid];
      for (int k = 0; k < 256; ++k) t = fmaf(h0z[k], W1[k * 128 + tid], t);
      h1z[tid] = fmaxf(t, 0.f) * wsc[tid];
    }
    __syncthreads();
    if (tid == 0) {
      float sz = 0.f;
      for (int p = 0; p < 128; ++p) sz += h1z[p];
      scores[0]  = sz;   // node 0 uses zero neighbor in the reference
      scores[NN] = sz;   // sentinel row
      // S seed: sentinel always in softmax; node 0 only if adj[0] != 0.
      *S = expf(sz) * (adj[0] != 0 ? 2.f : 1.f);
      *cnt = 0;
    }
  } else {
    int gid = (blockIdx.x - 1) * 256 + tid;
    if (gid < 8192) {              // W0 neighbor-half transpose: [256 out][256 k]
      int m = gid >> 5, a = gid & 31, k0 = a * 8;
      unsigned q0 = pk2(W0[(256 + k0 + 0) * 256 + m], W0[(256 + k0 + 1) * 256 + m]);
      unsigned q1 = pk2(W0[(256 + k0 + 2) * 256 + m], W0[(256 + k0 + 3) * 256 + m]);
      unsigned q2 = pk2(W0[(256 + k0 + 4) * 256 + m], W0[(256 + k0 + 5) * 256 + m]);
      unsigned q3 = pk2(W0[(256 + k0 + 6) * 256 + m], W0[(256 + k0 + 7) * 256 + m]);
      *(uint4*)(w0t + m * 512 + ((a ^ (m & 7)) << 4)) = make_uint4(q0, q1, q2, q3);
    } else if (gid < 12288) {      // W1 transpose, k-permuted: [128 out][256 k]
      int g2 = gid - 8192;
      int p = g2 >> 5, a = g2 & 31;
      int base = 32 * (a >> 2) + 16 * ((a >> 1) & 1) + 4 * (a & 1);
      unsigned q0 = pk2(W1[(base + 0)  * 128 + p], W1[(base + 1)  * 128 + p]);
      unsigned q1 = pk2(W1[(base + 2)  * 128 + p], W1[(base + 3)  * 128 + p]);
      unsigned q2 = pk2(W1[(base + 8)  * 128 + p], W1[(base + 9)  * 128 + p]);
      unsigned q3 = pk2(W1[(base + 10) * 128 + p], W1[(base + 11) * 128 + p]);
      *(uint4*)(w1t + p * 512 + ((a ^ (p & 7)) << 4)) = make_uint4(q0, q1, q2, q3);
    }
  }
}

// ---------------------------------------------------------------------------
// compact: idx[] = columns i in [1, NN) with adj[i] != 0 (order irrelevant).
// 49 blocks x 1024 threads x 4 elems; LDS aggregation -> ONE atomic per block
// (49 total; the previous version's 3128 same-address device atomics were the
// prime suspect for the 365 us total).
// ---------------------------------------------------------------------------
__global__ __launch_bounds__(1024) void
gnn_compact(const int* __restrict__ adj, int* __restrict__ idx, int* __restrict__ cnt)
{
  __shared__ int wc[64];     // [pass*16 + wave] counts -> exclusive prefix
  __shared__ int bbase;
  const int tid  = threadIdx.x;
  const int wave = tid >> 6, lane = tid & 63;
  const int R = blockIdx.x * 4096;

  unsigned long long mk[4];
#pragma unroll
  for (int p = 0; p < 4; ++p) {
    int i = R + p * 1024 + tid;
    bool f = (i > 0) && (i < NN) && (adj[i] != 0);
    mk[p] = __ballot(f);
  }
  if (lane == 0) {
#pragma unroll
    for (int p = 0; p < 4; ++p) wc[p * 16 + wave] = __popcll(mk[p]);
  }
  __syncthreads();
  if (tid == 0) {
    int run = 0;
    for (int e = 0; e < 64; ++e) { int v = wc[e]; wc[e] = run; run += v; }
    bbase = atomicAdd(cnt, run);
  }
  __syncthreads();
  const int b0 = bbase;
#pragma unroll
  for (int p = 0; p < 4; ++p) {
    if ((mk[p] >> lane) & 1ull) {
      int i = R + p * 1024 + tid;
      idx[b0 + wc[p * 16 + wave] + __popcll(mk[p] & ((1ull << lane) - 1ull))] = i;
    }
  }
}

// ---------------------------------------------------------------------------
// main fused MLP: block = 256 thr (4 waves), 128 compacted rows/block (32/wave).
// MFMA operands swapped: A = weight^T tiles (LDS, global_load_lds dwordx4,
// swizzled), B = per-node data (registers). Layer-1 C-layout feeds layer-2
// B-fragments DIRECTLY (k-permutation baked into w1t by prep). Each block also
// accumulates its partial sum of exp(score) into S (one atomic per block).
// ---------------------------------------------------------------------------
__global__ __launch_bounds__(256, 2) void
gnn_main(const float* __restrict__ feat, const char* __restrict__ w0t,
         const char* __restrict__ w1t, const float* __restrict__ c0g,
         const float* __restrict__ b1, const float* __restrict__ wsc,
         const int* __restrict__ idx, const int* __restrict__ cnt,
         float* __restrict__ scores, float* __restrict__ S)
{
  __shared__ __align__(16) char sW[2][32768];  // weight chunk double buffer
  __shared__ float c0s[256];
  __shared__ float b1s[128];
  __shared__ float wss[128];
  __shared__ float wsum[4];

  const int M = *cnt;
  if ((int)blockIdx.x * 128 >= M) return;

  const int tid  = threadIdx.x;
  const int wave = tid >> 6, lane = tid & 63;
  const int h = lane >> 5, nl = lane & 31;

  const int slot = blockIdx.x * 128 + wave * 32 + nl;
  const int node = idx[min(slot, M - 1)];

  auto stage = [&](int buf, const char* gsrc) {
    const char* gp = gsrc + (wave << 13) + (lane << 4);
    char* lp = &sW[buf][wave << 13];
#pragma unroll
    for (int i = 0; i < 8; ++i)
      __builtin_amdgcn_global_load_lds(
          (const __attribute__((address_space(1))) unsigned*)(gp + (i << 10)),
          (__attribute__((address_space(3))) unsigned*)(lp + (i << 10)),
          16, 0, 0);
  };

  stage(0, w0t);  // chunk 0 (W0^T rows 0..63) async while we load features

  // Feature B-fragments: B[k][n]: n = lane&31 (node), k = 16*kk + 8*h + j.
  FragU fB[16];
  const float4* frow = (const float4*)(feat + (size_t)node * 256);
#pragma unroll
  for (int kk = 0; kk < 16; ++kk) {
    float4 x = frow[4 * kk + 2 * h];
    float4 y = frow[4 * kk + 2 * h + 1];
    fB[kk].q[0] = pk2(x.x, x.y);
    fB[kk].q[1] = pk2(x.z, x.w);
    fB[kk].q[2] = pk2(y.x, y.y);
    fB[kk].q[3] = pk2(y.z, y.w);
  }

  c0s[tid] = c0g[tid];
  if (tid < 128) { b1s[tid] = b1[tid]; wss[tid] = wsc[tid]; }
  __syncthreads();

  // ---- layer 1: h0 = relu(c0 + W0n^T f) ; packed bf16 kept in registers ----
  unsigned h0p[8][8];
#pragma unroll
  for (int c = 0; c < 4; ++c) {
    stage((c + 1) & 1, (c < 3) ? (w0t + (c + 1) * 32768) : w1t);
    const char* Bp = sW[c & 1];
    f32x16 acc0, acc1;
#pragma unroll
    for (int i = 0; i < 16; ++i) { acc0[i] = 0.f; acc1[i] = 0.f; }
#pragma unroll
    for (int kk = 0; kk < 16; ++kk) {
      // A[m'][k]: m' = lane&31 (row in chunk), atom = 2*kk + h, XOR-swizzled
      bf16x8 a0 = *(const bf16x8*)(Bp + nl * 512        + (((2 * kk + h) ^ (nl & 7)) << 4));
      bf16x8 a1 = *(const bf16x8*)(Bp + (32 + nl) * 512 + (((2 * kk + h) ^ (nl & 7)) << 4));
      acc0 = __builtin_amdgcn_mfma_f32_32x32x16_bf16(a0, fB[kk].v, acc0, 0, 0, 0);
      acc1 = __builtin_amdgcn_mfma_f32_32x32x16_bf16(a1, fB[kk].v, acc1, 0, 0, 0);
    }
#pragma unroll
    for (int t = 0; t < 2; ++t) {
      const f32x16& ac = t ? acc1 : acc0;
      const int tile = c * 2 + t, nb = tile * 32;
#pragma unroll
      for (int g = 0; g < 4; ++g) {
        // C/D row = (reg&3) + 8*(reg>>2) + 4*h ; col = node
        float4 cv = *(const float4*)&c0s[nb + 8 * g + 4 * h];
        float v0 = fmaxf(ac[4 * g + 0] + cv.x, 0.f);
        float v1 = fmaxf(ac[4 * g + 1] + cv.y, 0.f);
        float v2 = fmaxf(ac[4 * g + 2] + cv.z, 0.f);
        float v3 = fmaxf(ac[4 * g + 3] + cv.w, 0.f);
        h0p[tile][2 * g + 0] = pk2(v0, v1);
        h0p[tile][2 * g + 1] = pk2(v2, v3);
      }
    }
    __syncthreads();
  }

  // ---- layer 2: h1 = relu(b1 + W1^T h0) ; score = h1 . w ----
  // h0p is consumed in its natural C-layout; w1t's k-permutation makes the
  // contraction line up without any cross-lane shuffle.
  f32x16 acc2[4];
#pragma unroll
  for (int t = 0; t < 4; ++t)
#pragma unroll
    for (int i = 0; i < 16; ++i) acc2[t][i] = 0.f;

#pragma unroll
  for (int c2 = 0; c2 < 2; ++c2) {
    if (c2 == 0) stage(1, w1t + 32768);  // chunk 5 = W1^T rows 64..127
    const char* Bp = sW[c2];             // chunk 4 landed in buf 0, 5 in buf 1
#pragma unroll
    for (int kk = 0; kk < 16; ++kk) {
      bf16x8 a0 = *(const bf16x8*)(Bp + nl * 512        + (((2 * kk + h) ^ (nl & 7)) << 4));
      bf16x8 a1 = *(const bf16x8*)(Bp + (32 + nl) * 512 + (((2 * kk + h) ^ (nl & 7)) << 4));
      FragU bb;
      const int tt = kk >> 1, p = kk & 1;
      bb.q[0] = h0p[tt][4 * p + 0];
      bb.q[1] = h0p[tt][4 * p + 1];
      bb.q[2] = h0p[tt][4 * p + 2];
      bb.q[3] = h0p[tt][4 * p + 3];
      acc2[c2 * 2 + 0] = __builtin_amdgcn_mfma_f32_32x32x16_bf16(a0, bb.v, acc2[c2 * 2 + 0], 0, 0, 0);
      acc2[c2 * 2 + 1] = __builtin_amdgcn_mfma_f32_32x32x16_bf16(a1, bb.v, acc2[c2 * 2 + 1], 0, 0, 0);
    }
    if (c2 == 0) __syncthreads();
  }

  float sc = 0.f;
#pragma unroll
  for (int pt = 0; pt < 4; ++pt) {
#pragma unroll
    for (int g = 0; g < 4; ++g) {
      float4 bv = *(const float4*)&b1s[pt * 32 + 8 * g + 4 * h];
      float4 wv = *(const float4*)&wss[pt * 32 + 8 * g + 4 * h];
      sc += fmaxf(acc2[pt][4 * g + 0] + bv.x, 0.f) * wv.x;
      sc += fmaxf(acc2[pt][4 * g + 1] + bv.y, 0.f) * wv.y;
      sc += fmaxf(acc2[pt][4 * g + 2] + bv.z, 0.f) * wv.z;
      sc += fmaxf(acc2[pt][4 * g + 3] + bv.w, 0.f) * wv.w;
    }
  }
  sc += __shfl_xor(sc, 32, 64);  // combine the two p-halves (same node)
  if (h == 0 && slot < M) scores[node] = sc;

  // ---- per-block partial softmax denominator (replaces gnn_reduce) ----
  float ex = (slot < M) ? expf(sc) : 0.f;   // both h halves hold sc -> sum is 2x
#pragma unroll
  for (int off = 32; off; off >>= 1) ex += __shfl_xor(ex, off, 64);
  if (lane == 0) wsum[wave] = ex * 0.5f;
  __syncthreads();
  if (tid == 0) atomicAdd(S, wsum[0] + wsum[1] + wsum[2] + wsum[3]);
}

// ---------------------------------------------------------------------------
__global__ void gnn_final(const int* __restrict__ adj, const float* __restrict__ scores,
                          const float* __restrict__ S, float* __restrict__ out)
{
  int i = blockIdx.x * blockDim.x + threadIdx.x;
  if (i > NN) return;
  bool m = (i == NN) || (adj[i] != 0);
  float Sv = *S;
  out[i] = m ? expf(scores[i]) / Sv : 0.f;
}

// ---------------------------------------------------------------------------
extern "C" void kernel_launch(void* const* d_in, const int* in_sizes, int n_in,
                              void* d_out, int out_size, void* d_ws, size_t ws_size,
                              hipStream_t stream)
{
  (void)in_sizes; (void)n_in; (void)out_size; (void)ws_size;
  const int*   adj  = (const int*)d_in[0];
  const float* feat = (const float*)d_in[1];
  const float* W0   = (const float*)d_in[2];
  const float* b0   = (const float*)d_in[3];
  const float* W1   = (const float*)d_in[4];
  const float* b1   = (const float*)d_in[5];
  const float* wsc  = (const float*)d_in[6];
  float* out = (float*)d_out;

  // workspace layout (≈1.8 MB)
  char* ws = (char*)d_ws;
  float* scores = (float*)ws;               // 200001 f32 (pad to 800256 B)
  char*  w0t    = ws + 800256;              // 131072 B  W0n^T bf16, swizzled
  char*  w1t    = ws + 931328;              // 65536 B   W1^T  bf16, swizzled+permuted
  float* c0g    = (float*)(ws + 996864);    // 256 f32
  float* S      = (float*)(ws + 997888);    // 1 f32
  int*   cnt    = (int*)(ws + 997904);      // 1 i32
  int*   idxb   = (int*)(ws + 997952);      // 200000 i32

  gnn_prep   <<<49,   256,  0, stream>>>(adj, feat, W0, b0, W1, b1, wsc, c0g, w0t, w1t, scores, S, cnt);
  gnn_compact<<<49,   1024, 0, stream>>>(adj, idxb, cnt);
  gnn_main   <<<1563, 256,  0, stream>>>(feat, w0t, w1t, c0g, b1, wsc, idxb, cnt, scores, S);
  gnn_final  <<<782,  256,  0, stream>>>(adj, scores, S, out);
}

// Round 3
// 317.927 us; speedup vs baseline: 1.1491x; 1.0118x over previous
//
#include <hip/hip_runtime.h>
#include <stdint.h>

// Problem constants (fixed by the reference).
#define NN    200000   // nodes
#define NTOT  200001   // nodes + sentinel
#define NPART 1563     // main-grid blocks / partial-sum slots

typedef short bf16x8 __attribute__((ext_vector_type(8)));   // 8 bf16 = 4 VGPRs
typedef float f32x16 __attribute__((ext_vector_type(16)));  // 32x32 MFMA acc

union FragU { bf16x8 v; unsigned q[4]; };

// float -> bf16 round-to-nearest-even (finite inputs)
__device__ __forceinline__ unsigned bfrne(float x) {
  unsigned u = __float_as_uint(x);
  return (u + 0x7fffu + ((u >> 16) & 1u)) >> 16;
}
__device__ __forceinline__ unsigned pk2(float a, float b) {
  return bfrne(a) | (bfrne(b) << 16);
}

// ---------------------------------------------------------------------------
// prep+compact fused (independent work overlapped in one dispatch):
//  block 0      : c0 = f0^T W0[:256]+b0; zero-neighbor score (node 0, sentinel);
//                 S seeded with their exp() contributions.
//  blocks 1-48  : W0n^T / W1^T -> bf16, 16B atoms XOR-swizzled (atom a at
//                 a ^ (row&7)); w1t bakes in the k-permutation matching the
//                 layer-1 MFMA C-layout (atom a: tt=a>>2, p'=(a>>1)&1, h=a&1;
//                 pos j holds k = 32tt+16p'+4h+8(j>>2)+(j&3)).
//  blocks 49-97 : compact idx[] = {i in [1,NN): adj[i]!=0}; 4096 elems/block,
//                 LDS prefix -> ONE atomic per block (cnt pre-zeroed by a
//                 4-byte hipMemsetAsync so there is no race with block 0).
// ---------------------------------------------------------------------------
__global__ void gnn_prep(const int* __restrict__ adj, const float* __restrict__ feat,
                         const float* __restrict__ W0, const float* __restrict__ b0,
                         const float* __restrict__ W1, const float* __restrict__ b1,
                         const float* __restrict__ wsc, float* __restrict__ c0g,
                         char* __restrict__ w0t, char* __restrict__ w1t,
                         float* __restrict__ scores, float* __restrict__ S,
                         int* __restrict__ idx, int* __restrict__ cnt)
{
  const int tid = threadIdx.x;
  if (blockIdx.x == 0) {
    __shared__ float h0z[256];
    __shared__ float h1z[128];
    float a = b0[tid];
    for (int f = 0; f < 256; ++f) a = fmaf(feat[f], W0[f * 256 + tid], a);
    c0g[tid] = a;
    h0z[tid] = fmaxf(a, 0.f);
    __syncthreads();
    if (tid < 128) {
      float t = b1[tid];
      for (int k = 0; k < 256; ++k) t = fmaf(h0z[k], W1[k * 128 + tid], t);
      h1z[tid] = fmaxf(t, 0.f) * wsc[tid];
    }
    __syncthreads();
    if (tid == 0) {
      float sz = 0.f;
      for (int p = 0; p < 128; ++p) sz += h1z[p];
      scores[0]  = sz;   // node 0 uses zero neighbor in the reference
      scores[NN] = sz;   // sentinel row
      // S seed: sentinel always in softmax; node 0 only if adj[0] != 0.
      *S = expf(sz) * (adj[0] != 0 ? 2.f : 1.f);
    }
  } else if (blockIdx.x < 49) {
    int gid = (blockIdx.x - 1) * 256 + tid;
    if (gid < 8192) {              // W0 neighbor-half transpose: [256 out][256 k]
      int m = gid >> 5, a = gid & 31, k0 = a * 8;
      unsigned q0 = pk2(W0[(256 + k0 + 0) * 256 + m], W0[(256 + k0 + 1) * 256 + m]);
      unsigned q1 = pk2(W0[(256 + k0 + 2) * 256 + m], W0[(256 + k0 + 3) * 256 + m]);
      unsigned q2 = pk2(W0[(256 + k0 + 4) * 256 + m], W0[(256 + k0 + 5) * 256 + m]);
      unsigned q3 = pk2(W0[(256 + k0 + 6) * 256 + m], W0[(256 + k0 + 7) * 256 + m]);
      *(uint4*)(w0t + m * 512 + ((a ^ (m & 7)) << 4)) = make_uint4(q0, q1, q2, q3);
    } else if (gid < 12288) {      // W1 transpose, k-permuted: [128 out][256 k]
      int g2 = gid - 8192;
      int p = g2 >> 5, a = g2 & 31;
      int base = 32 * (a >> 2) + 16 * ((a >> 1) & 1) + 4 * (a & 1);
      unsigned q0 = pk2(W1[(base + 0)  * 128 + p], W1[(base + 1)  * 128 + p]);
      unsigned q1 = pk2(W1[(base + 2)  * 128 + p], W1[(base + 3)  * 128 + p]);
      unsigned q2 = pk2(W1[(base + 8)  * 128 + p], W1[(base + 9)  * 128 + p]);
      unsigned q3 = pk2(W1[(base + 10) * 128 + p], W1[(base + 11) * 128 + p]);
      *(uint4*)(w1t + p * 512 + ((a ^ (p & 7)) << 4)) = make_uint4(q0, q1, q2, q3);
    }
  } else {
    // ---- compact: region of 4096 elements, 16 passes of 256 threads ----
    __shared__ int wc[64];     // [pass*4 + wave] counts -> exclusive prefix
    __shared__ int bbase;
    const int wave = tid >> 6, lane = tid & 63;
    const int R = (blockIdx.x - 49) * 4096;

    unsigned long long mk[16];
#pragma unroll
    for (int p = 0; p < 16; ++p) {
      int i = R + p * 256 + tid;
      bool f = (i > 0) && (i < NN) && (adj[i] != 0);
      mk[p] = __ballot(f);
      if (lane == 0) wc[p * 4 + wave] = __popcll(mk[p]);
    }
    __syncthreads();
    if (tid == 0) {
      int run = 0;
      for (int e = 0; e < 64; ++e) { int v = wc[e]; wc[e] = run; run += v; }
      bbase = atomicAdd(cnt, run);
    }
    __syncthreads();
    const int bb = bbase;
#pragma unroll
    for (int p = 0; p < 16; ++p) {
      if ((mk[p] >> lane) & 1ull) {
        int i = R + p * 256 + tid;
        idx[bb + wc[p * 4 + wave] + __popcll(mk[p] & ((1ull << lane) - 1ull))] = i;
      }
    }
  }
}

// ---------------------------------------------------------------------------
// main fused MLP: block = 256 thr (4 waves), 128 compacted rows/block (32/wave).
// MFMA operands swapped: A = weight^T tiles (LDS, global_load_lds dwordx4,
// swizzled), B = per-node data (registers). Layer-1 C-layout feeds layer-2
// B-fragments DIRECTLY (k-permutation baked into w1t by prep). Each block
// writes its partial sum of exp(score) to a PRIVATE slot — no same-address
// atomics (R1->R2 calibration: ~12 ns/atomic fully on the critical path).
// ---------------------------------------------------------------------------
__global__ __launch_bounds__(256, 2) void
gnn_main(const float* __restrict__ feat, const char* __restrict__ w0t,
         const char* __restrict__ w1t, const float* __restrict__ c0g,
         const float* __restrict__ b1, const float* __restrict__ wsc,
         const int* __restrict__ idx, const int* __restrict__ cnt,
         float* __restrict__ scores, float* __restrict__ partial)
{
  __shared__ __align__(16) char sW[2][32768];  // weight chunk double buffer
  __shared__ float c0s[256];
  __shared__ float b1s[128];
  __shared__ float wss[128];
  __shared__ float wsum[4];

  const int tid = threadIdx.x;
  const int M = *cnt;
  if ((int)blockIdx.x * 128 >= M) {
    if (tid == 0) partial[blockIdx.x] = 0.f;   // ws is poisoned: must zero
    return;
  }

  const int wave = tid >> 6, lane = tid & 63;
  const int h = lane >> 5, nl = lane & 31;

  const int slot = blockIdx.x * 128 + wave * 32 + nl;
  const int node = idx[min(slot, M - 1)];

  auto stage = [&](int buf, const char* gsrc) {
    const char* gp = gsrc + (wave << 13) + (lane << 4);
    char* lp = &sW[buf][wave << 13];
#pragma unroll
    for (int i = 0; i < 8; ++i)
      __builtin_amdgcn_global_load_lds(
          (const __attribute__((address_space(1))) unsigned*)(gp + (i << 10)),
          (__attribute__((address_space(3))) unsigned*)(lp + (i << 10)),
          16, 0, 0);
  };

  stage(0, w0t);  // chunk 0 (W0^T rows 0..63) async while we load features

  // Feature B-fragments: B[k][n]: n = lane&31 (node), k = 16*kk + 8*h + j.
  FragU fB[16];
  const float4* frow = (const float4*)(feat + (size_t)node * 256);
#pragma unroll
  for (int kk = 0; kk < 16; ++kk) {
    float4 x = frow[4 * kk + 2 * h];
    float4 y = frow[4 * kk + 2 * h + 1];
    fB[kk].q[0] = pk2(x.x, x.y);
    fB[kk].q[1] = pk2(x.z, x.w);
    fB[kk].q[2] = pk2(y.x, y.y);
    fB[kk].q[3] = pk2(y.z, y.w);
  }

  c0s[tid] = c0g[tid];
  if (tid < 128) { b1s[tid] = b1[tid]; wss[tid] = wsc[tid]; }
  __syncthreads();

  // ---- layer 1: h0 = relu(c0 + W0n^T f) ; packed bf16 kept in registers ----
  unsigned h0p[8][8];
#pragma unroll
  for (int c = 0; c < 4; ++c) {
    stage((c + 1) & 1, (c < 3) ? (w0t + (c + 1) * 32768) : w1t);
    const char* Bp = sW[c & 1];
    f32x16 acc0, acc1;
#pragma unroll
    for (int i = 0; i < 16; ++i) { acc0[i] = 0.f; acc1[i] = 0.f; }
#pragma unroll
    for (int kk = 0; kk < 16; ++kk) {
      // A[m'][k]: m' = lane&31 (row in chunk), atom = 2*kk + h, XOR-swizzled
      bf16x8 a0 = *(const bf16x8*)(Bp + nl * 512        + (((2 * kk + h) ^ (nl & 7)) << 4));
      bf16x8 a1 = *(const bf16x8*)(Bp + (32 + nl) * 512 + (((2 * kk + h) ^ (nl & 7)) << 4));
      acc0 = __builtin_amdgcn_mfma_f32_32x32x16_bf16(a0, fB[kk].v, acc0, 0, 0, 0);
      acc1 = __builtin_amdgcn_mfma_f32_32x32x16_bf16(a1, fB[kk].v, acc1, 0, 0, 0);
    }
#pragma unroll
    for (int t = 0; t < 2; ++t) {
      const f32x16& ac = t ? acc1 : acc0;
      const int tile = c * 2 + t, nb = tile * 32;
#pragma unroll
      for (int g = 0; g < 4; ++g) {
        // C/D row = (reg&3) + 8*(reg>>2) + 4*h ; col = node
        float4 cv = *(const float4*)&c0s[nb + 8 * g + 4 * h];
        float v0 = fmaxf(ac[4 * g + 0] + cv.x, 0.f);
        float v1 = fmaxf(ac[4 * g + 1] + cv.y, 0.f);
        float v2 = fmaxf(ac[4 * g + 2] + cv.z, 0.f);
        float v3 = fmaxf(ac[4 * g + 3] + cv.w, 0.f);
        h0p[tile][2 * g + 0] = pk2(v0, v1);
        h0p[tile][2 * g + 1] = pk2(v2, v3);
      }
    }
    __syncthreads();
  }

  // ---- layer 2: h1 = relu(b1 + W1^T h0) ; score = h1 . w ----
  // h0p is consumed in its natural C-layout; w1t's k-permutation makes the
  // contraction line up without any cross-lane shuffle.
  f32x16 acc2[4];
#pragma unroll
  for (int t = 0; t < 4; ++t)
#pragma unroll
    for (int i = 0; i < 16; ++i) acc2[t][i] = 0.f;

#pragma unroll
  for (int c2 = 0; c2 < 2; ++c2) {
    if (c2 == 0) stage(1, w1t + 32768);  // chunk 5 = W1^T rows 64..127
    const char* Bp = sW[c2];             // chunk 4 landed in buf 0, 5 in buf 1
#pragma unroll
    for (int kk = 0; kk < 16; ++kk) {
      bf16x8 a0 = *(const bf16x8*)(Bp + nl * 512        + (((2 * kk + h) ^ (nl & 7)) << 4));
      bf16x8 a1 = *(const bf16x8*)(Bp + (32 + nl) * 512 + (((2 * kk + h) ^ (nl & 7)) << 4));
      FragU bb;
      const int tt = kk >> 1, p = kk & 1;
      bb.q[0] = h0p[tt][4 * p + 0];
      bb.q[1] = h0p[tt][4 * p + 1];
      bb.q[2] = h0p[tt][4 * p + 2];
      bb.q[3] = h0p[tt][4 * p + 3];
      acc2[c2 * 2 + 0] = __builtin_amdgcn_mfma_f32_32x32x16_bf16(a0, bb.v, acc2[c2 * 2 + 0], 0, 0, 0);
      acc2[c2 * 2 + 1] = __builtin_amdgcn_mfma_f32_32x32x16_bf16(a1, bb.v, acc2[c2 * 2 + 1], 0, 0, 0);
    }
    if (c2 == 0) __syncthreads();
  }

  float sc = 0.f;
#pragma unroll
  for (int pt = 0; pt < 4; ++pt) {
#pragma unroll
    for (int g = 0; g < 4; ++g) {
      float4 bv = *(const float4*)&b1s[pt * 32 + 8 * g + 4 * h];
      float4 wv = *(const float4*)&wss[pt * 32 + 8 * g + 4 * h];
      sc += fmaxf(acc2[pt][4 * g + 0] + bv.x, 0.f) * wv.x;
      sc += fmaxf(acc2[pt][4 * g + 1] + bv.y, 0.f) * wv.y;
      sc += fmaxf(acc2[pt][4 * g + 2] + bv.z, 0.f) * wv.z;
      sc += fmaxf(acc2[pt][4 * g + 3] + bv.w, 0.f) * wv.w;
    }
  }
  sc += __shfl_xor(sc, 32, 64);  // combine the two p-halves (same node)
  if (h == 0 && slot < M) scores[node] = sc;

  // ---- per-block partial softmax denominator -> PRIVATE slot (no atomics) --
  float ex = (slot < M) ? expf(sc) : 0.f;   // both h halves hold sc -> sum is 2x
#pragma unroll
  for (int off = 32; off; off >>= 1) ex += __shfl_xor(ex, off, 64);
  if (lane == 0) wsum[wave] = ex * 0.5f;
  __syncthreads();
  if (tid == 0) partial[blockIdx.x] = wsum[0] + wsum[1] + wsum[2] + wsum[3];
}

// ---------------------------------------------------------------------------
// final: every block reduces the 1563 partials (L2-hot) + seed, then writes
// the masked softmax outputs.
// ---------------------------------------------------------------------------
__global__ void gnn_final(const int* __restrict__ adj, const float* __restrict__ scores,
                          const float* __restrict__ S, const float* __restrict__ partial,
                          float* __restrict__ out)
{
  __shared__ float red[4];
  __shared__ float Svs;
  const int tid = threadIdx.x;
  float loc = 0.f;
  for (int j = tid; j < NPART; j += 256) loc += partial[j];
#pragma unroll
  for (int off = 32; off; off >>= 1) loc += __shfl_xor(loc, off, 64);
  if ((tid & 63) == 0) red[tid >> 6] = loc;
  __syncthreads();
  if (tid == 0) Svs = *S + red[0] + red[1] + red[2] + red[3];
  __syncthreads();
  const float Sv = Svs;

  int i = blockIdx.x * 256 + tid;
  if (i > NN) return;
  bool m = (i == NN) || (adj[i] != 0);
  out[i] = m ? expf(scores[i]) / Sv : 0.f;
}

// ---------------------------------------------------------------------------
extern "C" void kernel_launch(void* const* d_in, const int* in_sizes, int n_in,
                              void* d_out, int out_size, void* d_ws, size_t ws_size,
                              hipStream_t stream)
{
  (void)in_sizes; (void)n_in; (void)out_size; (void)ws_size;
  const int*   adj  = (const int*)d_in[0];
  const float* feat = (const float*)d_in[1];
  const float* W0   = (const float*)d_in[2];
  const float* b0   = (const float*)d_in[3];
  const float* W1   = (const float*)d_in[4];
  const float* b1   = (const float*)d_in[5];
  const float* wsc  = (const float*)d_in[6];
  float* out = (float*)d_out;

  // workspace layout (≈1.81 MB)
  char* ws = (char*)d_ws;
  float* scores  = (float*)ws;               // 200001 f32 (pad to 800256 B)
  char*  w0t     = ws + 800256;              // 131072 B  W0n^T bf16, swizzled
  char*  w1t     = ws + 931328;              // 65536 B   W1^T  bf16, swizzled+permuted
  float* c0g     = (float*)(ws + 996864);    // 256 f32
  float* S       = (float*)(ws + 997888);    // 1 f32 (seed)
  int*   cnt     = (int*)(ws + 997904);      // 1 i32
  int*   idxb    = (int*)(ws + 997952);      // 200000 i32
  float* partial = (float*)(ws + 1797952);   // 1563 f32

  hipMemsetAsync(cnt, 0, 4, stream);         // compact runs concurrently with prep
  gnn_prep <<<98,    256, 0, stream>>>(adj, feat, W0, b0, W1, b1, wsc, c0g, w0t, w1t, scores, S, idxb, cnt);
  gnn_main <<<NPART, 256, 0, stream>>>(feat, w0t, w1t, c0g, b1, wsc, idxb, cnt, scores, partial);
  gnn_final<<<782,   256, 0, stream>>>(adj, scores, S, partial, out);
}